// Round 1
// baseline (9997.924 us; speedup 1.0000x reference)
//
#include <hip/hip_runtime.h>
#include <hip/hip_bf16.h>
#include <math.h>

#define H_ 16
#define W_ 16
#define L_ 256
#define BATCH 64
#define CIMG 512
#define CPC 256
#define COMB_ 770
#define DIMC 128
#define DMODEL 1282
#define DINNER 2564
#define DXZ 5128
#define DTRANK 81
#define NSTATE 16
#define NPOS 275   // 25 + 81 + 169
#define DBLW 113   // 81 + 16 + 16

// ---------------------------------------------------------------------------
// helpers
// ---------------------------------------------------------------------------
__device__ __forceinline__ float comb_val(const float* __restrict__ x,
                                          const float* __restrict__ pc,
                                          int bg, int c, int h, int w) {
  if (c < CIMG)    return x[(((size_t)bg * CIMG + c) << 8) + (h << 4) + w];
  if (c == CIMG)   return -0.3f + 0.04f * (float)w;   // meshgrid X = xx[w]
  if (c == CIMG+1) return -0.3f + 0.04f * (float)h;   // meshgrid Y = xx[h]
  return pc[bg * CPC + (c - (CIMG + 2))];
}

__device__ __forceinline__ void idx_to_scale(int idx, int& s, int& o, int& p, int& base) {
  if (idx < 25)       { s = 5;  base = 0; }
  else if (idx < 106) { s = 9;  base = 25; }
  else                { s = 13; base = 106; }
  int r = idx - base;
  o = r / s; p = r - o * s;
}

// ---------------------------------------------------------------------------
// K1: adaptive-avg-pool of comb for scales {5,9,13} -> P[bl][c][idx(275)]
// ---------------------------------------------------------------------------
__global__ __launch_bounds__(256) void pool_kernel(
    const float* __restrict__ x, const float* __restrict__ pc,
    float* __restrict__ P, int b0) {
  int t = blockIdx.x * 256 + threadIdx.x;
  if (t >= COMB_ * NPOS) return;
  int bl = blockIdx.y;
  int bg = b0 + bl;
  int c = t / NPOS;
  int idx = t - c * NPOS;
  int s, o, p, base; idx_to_scale(idx, s, o, p, base);
  int hs = (o * 16) / s, he = ((o + 1) * 16 + s - 1) / s;
  int ws2 = (p * 16) / s, we = ((p + 1) * 16 + s - 1) / s;
  float sum = 0.f;
  for (int h = hs; h < he; h++)
    for (int w = ws2; w < we; w++)
      sum += comb_val(x, pc, bg, c, h, w);
  P[((size_t)bl * COMB_ + c) * NPOS + idx] = sum / (float)((he - hs) * (we - ws2));
}

// ---------------------------------------------------------------------------
// K2: 1x1 conv + BN + ReLU6 on pooled maps (scales 1..3) -> Y[bl][idx][d]
// one block per (d, bl); w rows for the 3 scales staged in LDS
// ---------------------------------------------------------------------------
__global__ __launch_bounds__(256) void cbr_small_kernel(
    const float* __restrict__ P, const float* __restrict__ conv_w,
    const float* __restrict__ gamma, const float* __restrict__ beta,
    const float* __restrict__ mean, const float* __restrict__ var,
    float* __restrict__ Y) {
  int d = blockIdx.x, bl = blockIdx.y;
  __shared__ float wsm[3 * COMB_];
  for (int e = threadIdx.x; e < 3 * COMB_; e += 256) {
    int i = e / COMB_, c = e - i * COMB_;
    wsm[e] = conv_w[((size_t)(i + 1) * DIMC + d) * COMB_ + c];
  }
  __syncthreads();
  for (int idx = threadIdx.x; idx < NPOS; idx += 256) {
    int i = (idx < 25) ? 1 : (idx < 106 ? 2 : 3);
    const float* wr = &wsm[(i - 1) * COMB_];
    const float* pr = &P[(size_t)bl * COMB_ * NPOS + idx];
    float acc = 0.f;
    for (int c = 0; c < COMB_; c++) acc += wr[c] * pr[(size_t)c * NPOS];
    int bi = i * DIMC + d;
    float inv = rsqrtf(var[bi] + 1e-5f) * gamma[bi];
    float bs = beta[bi] - mean[bi] * inv;
    float v = acc * inv + bs;
    v = fminf(fmaxf(v, 0.f), 6.f);
    Y[((size_t)bl * NPOS + idx) * DIMC + d] = v;
  }
}

// ---------------------------------------------------------------------------
// K3: scale-0 path: CBR at full res then spatial mean -> y0[bl][d]
// one block per (d, bl); thread = position l; weight row in LDS
// ---------------------------------------------------------------------------
__global__ __launch_bounds__(256) void cbr0_kernel(
    const float* __restrict__ x, const float* __restrict__ pc,
    const float* __restrict__ conv_w,
    const float* __restrict__ gamma, const float* __restrict__ beta,
    const float* __restrict__ mean, const float* __restrict__ var,
    float* __restrict__ y0, int b0) {
  int d = blockIdx.x, bl = blockIdx.y, bg = b0 + bl;
  __shared__ float w0[COMB_];
  __shared__ float red[4];
  for (int e = threadIdx.x; e < COMB_; e += 256)
    w0[e] = conv_w[(size_t)d * COMB_ + e];
  __syncthreads();
  int l = threadIdx.x;
  int h = l >> 4, w = l & 15;
  float acc = 0.f;
  for (int c = 0; c < CIMG; c++)
    acc += w0[c] * x[(((size_t)bg * CIMG + c) << 8) + l];
  acc += w0[CIMG]     * (-0.3f + 0.04f * (float)w);
  acc += w0[CIMG + 1] * (-0.3f + 0.04f * (float)h);
  for (int c = 0; c < CPC; c++)
    acc += w0[CIMG + 2 + c] * pc[bg * CPC + c];
  float inv = rsqrtf(var[d] + 1e-5f) * gamma[d];
  float bs = beta[d] - mean[d] * inv;
  float v = fminf(fmaxf(acc * inv + bs, 0.f), 6.f);
  #pragma unroll
  for (int off = 32; off > 0; off >>= 1) v += __shfl_down(v, off);
  if ((threadIdx.x & 63) == 0) red[threadIdx.x >> 6] = v;
  __syncthreads();
  if (threadIdx.x == 0)
    y0[bl * DIMC + d] = (red[0] + red[1] + red[2] + red[3]) * (1.f / 256.f);
}

// ---------------------------------------------------------------------------
// K4: assemble seq[bl][l][c] (c: 770 comb | 128 y0-bcast | 3x128 bilinear-up)
// ---------------------------------------------------------------------------
__global__ __launch_bounds__(256) void seq_kernel(
    const float* __restrict__ x, const float* __restrict__ pc,
    const float* __restrict__ y0, const float* __restrict__ Y,
    float* __restrict__ seq, int b0) {
  int l = blockIdx.x, bl = blockIdx.y, bg = b0 + bl;
  int h = l >> 4, w = l & 15;
  float* sr = &seq[((size_t)bl * L_ + l) * DMODEL];
  for (int c = threadIdx.x; c < DMODEL; c += 256) {
    float v;
    if (c < COMB_) {
      v = comb_val(x, pc, bg, c, h, w);
    } else if (c < COMB_ + DIMC) {
      v = y0[bl * DIMC + (c - COMB_)];
    } else {
      int cc = c - (COMB_ + DIMC);
      int si = cc >> 7;
      int d = cc & 127;
      int s    = (si == 0) ? 5 : ((si == 1) ? 9 : 13);
      int base = (si == 0) ? 0 : ((si == 1) ? 25 : 106);
      float srch = (h + 0.5f) * (float)s * (1.f / 16.f) - 0.5f;
      srch = fminf(fmaxf(srch, 0.f), (float)(s - 1));
      int o0 = (int)floorf(srch);
      float fh = srch - (float)o0;
      int o1 = min(o0 + 1, s - 1);
      float srcw = (w + 0.5f) * (float)s * (1.f / 16.f) - 0.5f;
      srcw = fminf(fmaxf(srcw, 0.f), (float)(s - 1));
      int p0 = (int)floorf(srcw);
      float fw = srcw - (float)p0;
      int p1 = min(p0 + 1, s - 1);
      const float* Yb = &Y[((size_t)bl * NPOS + base) * DIMC + d];
      float v00 = Yb[(size_t)(o0 * s + p0) * DIMC];
      float v01 = Yb[(size_t)(o0 * s + p1) * DIMC];
      float v10 = Yb[(size_t)(o1 * s + p0) * DIMC];
      float v11 = Yb[(size_t)(o1 * s + p1) * DIMC];
      v = (1.f - fh) * ((1.f - fw) * v00 + fw * v01)
        +        fh  * ((1.f - fw) * v10 + fw * v11);
    }
    sr[c] = v;
  }
}

// ---------------------------------------------------------------------------
// K5: generic fp32 GEMM  C[M,N] = A[M,K(lda)] * W[N,K(ldw)]^T
// 64x64 tile, 4x4 per thread. mode 0: plain; 1: +bias softplus; 2: write
// transposed into d_out as out[b][n][l]
// ---------------------------------------------------------------------------
__global__ __launch_bounds__(256) void gemm_kernel(
    const float* __restrict__ A, int lda,
    const float* __restrict__ Wt, int ldw,
    float* __restrict__ C, int ldc,
    int M, int N, int K, int mode,
    const float* __restrict__ bias,
    float* __restrict__ outT, int b0) {
  __shared__ float As[16][68];
  __shared__ float Ws[16][68];
  int tid = threadIdx.x;
  int tx = tid & 15, ty = tid >> 4;
  int m0 = blockIdx.y << 6, n0 = blockIdx.x << 6;
  float acc[4][4] = {{0.f}};
  for (int k0 = 0; k0 < K; k0 += 16) {
    #pragma unroll
    for (int i = 0; i < 4; i++) {
      int e = tid + (i << 8);
      int mm = e >> 4, kk = e & 15;
      int gm = m0 + mm, gk = k0 + kk;
      As[kk][mm] = (gm < M && gk < K) ? A[(size_t)gm * lda + gk] : 0.f;
      int gn = n0 + mm;
      Ws[kk][mm] = (gn < N && gk < K) ? Wt[(size_t)gn * ldw + gk] : 0.f;
    }
    __syncthreads();
    #pragma unroll
    for (int kk = 0; kk < 16; kk++) {
      float a[4], b[4];
      #pragma unroll
      for (int i = 0; i < 4; i++) a[i] = As[kk][(ty << 2) + i];
      #pragma unroll
      for (int j = 0; j < 4; j++) b[j] = Ws[kk][(tx << 2) + j];
      #pragma unroll
      for (int i = 0; i < 4; i++)
        #pragma unroll
        for (int j = 0; j < 4; j++) acc[i][j] += a[i] * b[j];
    }
    __syncthreads();
  }
  #pragma unroll
  for (int i = 0; i < 4; i++) {
    int gm = m0 + (ty << 2) + i;
    if (gm >= M) continue;
    #pragma unroll
    for (int j = 0; j < 4; j++) {
      int gn = n0 + (tx << 2) + j;
      if (gn >= N) continue;
      float vv = acc[i][j];
      if (mode == 1) {
        vv += bias[gn];
        vv = (vv > 20.f) ? vv : log1pf(expf(vv));
        C[(size_t)gm * ldc + gn] = vv;
      } else if (mode == 2) {
        int b = b0 + (gm >> 8), l = gm & 255;
        outT[(((size_t)b * DMODEL + gn) << 8) + l] = vv;
      } else {
        C[(size_t)gm * ldc + gn] = vv;
      }
    }
  }
}

// ---------------------------------------------------------------------------
// K6: depthwise causal conv1d (k=4) + bias + silu.  u_pre is xz[:, 0:2564]
// ---------------------------------------------------------------------------
__global__ __launch_bounds__(256) void conv1d_kernel(
    const float* __restrict__ xz, const float* __restrict__ cw,
    const float* __restrict__ cb, float* __restrict__ v) {
  int d = blockIdx.x * 256 + threadIdx.x;
  if (d >= DINNER) return;
  int m = blockIdx.y;
  int l = m & 255;
  float acc = cb[d];
  #pragma unroll
  for (int j = 0; j < 4; j++) {
    int ll = l - 3 + j;
    if (ll >= 0) acc += cw[d * 4 + j] * xz[(size_t)(m - 3 + j) * DXZ + d];
  }
  v[(size_t)m * DINNER + d] = acc / (1.f + __expf(-acc));
}

// ---------------------------------------------------------------------------
// K7: selective scan. one thread per (bl, d); h[16] in registers.
// reads dt from dty, overwrites dty with (y + u*D) * silu(z)
// ---------------------------------------------------------------------------
__global__ __launch_bounds__(256) void scan_kernel(
    float* __restrict__ dty,
    const float* __restrict__ v, const float* __restrict__ xz,
    const float* __restrict__ dbl, const float* __restrict__ A_log,
    const float* __restrict__ Dv) {
  int d = blockIdx.x * 256 + threadIdx.x;
  if (d >= DINNER) return;
  int bl = blockIdx.y;
  float A[NSTATE], hst[NSTATE];
  #pragma unroll
  for (int n = 0; n < NSTATE; n++) {
    A[n] = -__expf(A_log[d * NSTATE + n]);
    hst[n] = 0.f;
  }
  float Dd = Dv[d];
  for (int l = 0; l < L_; l++) {
    size_t m = (size_t)bl * L_ + l;
    float dt = dty[m * DINNER + d];
    float uu = v[m * DINNER + d];
    float zz = xz[m * DXZ + DINNER + d];
    const float* bc = &dbl[m * DBLW];
    float du = dt * uu;
    float y = 0.f;
    #pragma unroll
    for (int n = 0; n < NSTATE; n++) {
      float dA = __expf(dt * A[n]);
      hst[n] = dA * hst[n] + du * bc[DTRANK + n];
      y += hst[n] * bc[DTRANK + NSTATE + n];
    }
    float val = (y + uu * Dd) * (zz / (1.f + __expf(-zz)));
    dty[m * DINNER + d] = val;
  }
}

// ---------------------------------------------------------------------------
// launch
// ---------------------------------------------------------------------------
extern "C" void kernel_launch(void* const* d_in, const int* in_sizes, int n_in,
                              void* d_out, int out_size, void* d_ws, size_t ws_size,
                              hipStream_t stream) {
  const float* x         = (const float*)d_in[0];
  const float* pc        = (const float*)d_in[1];
  const float* conv_w    = (const float*)d_in[2];
  const float* bn_gamma  = (const float*)d_in[3];
  const float* bn_beta   = (const float*)d_in[4];
  const float* bn_mean   = (const float*)d_in[5];
  const float* bn_var    = (const float*)d_in[6];
  const float* in_proj_w = (const float*)d_in[7];
  const float* conv1d_w  = (const float*)d_in[8];
  const float* conv1d_b  = (const float*)d_in[9];
  const float* x_proj_w  = (const float*)d_in[10];
  const float* dt_proj_w = (const float*)d_in[11];
  const float* dt_proj_b = (const float*)d_in[12];
  const float* A_log     = (const float*)d_in[13];
  const float* Dvec      = (const float*)d_in[14];
  const float* out_proj_w= (const float*)d_in[15];
  float* out = (float*)d_out;

  auto al = [](size_t vv) { return (vv + 255) & ~(size_t)255; };
  auto calc = [&](int bc) -> size_t {
    size_t Mc = (size_t)bc * L_;
    size_t s = 0;
    s += al(Mc * DMODEL * 4);                 // seq
    s += al((size_t)bc * COMB_ * NPOS * 4);   // P
    s += al((size_t)bc * NPOS * DIMC * 4);    // Y
    s += al((size_t)bc * DIMC * 4);           // y0
    s += al(Mc * DXZ * 4);                    // xz
    s += al(Mc * DINNER * 4);                 // v
    s += al(Mc * DBLW * 4);                   // dbl
    s += al(Mc * DINNER * 4);                 // dt/y
    return s;
  };
  int Bc = 64;
  while (Bc > 1 && calc(Bc) > ws_size) Bc >>= 1;

  size_t Mc = (size_t)Bc * L_;
  char* base = (char*)d_ws;
  size_t off = 0;
  float* seqb = (float*)(base + off); off += al(Mc * DMODEL * 4);
  float* Pb   = (float*)(base + off); off += al((size_t)Bc * COMB_ * NPOS * 4);
  float* Yb   = (float*)(base + off); off += al((size_t)Bc * NPOS * DIMC * 4);
  float* y0b  = (float*)(base + off); off += al((size_t)Bc * DIMC * 4);
  float* xzb  = (float*)(base + off); off += al(Mc * DXZ * 4);
  float* vb   = (float*)(base + off); off += al(Mc * DINNER * 4);
  float* dblb = (float*)(base + off); off += al(Mc * DBLW * 4);
  float* dtb  = (float*)(base + off); off += al(Mc * DINNER * 4);

  for (int b0 = 0; b0 < BATCH; b0 += Bc) {
    int Mci = Bc * L_;
    // PPM
    pool_kernel<<<dim3((COMB_ * NPOS + 255) / 256, Bc), 256, 0, stream>>>(x, pc, Pb, b0);
    cbr_small_kernel<<<dim3(DIMC, Bc), 256, 0, stream>>>(Pb, conv_w, bn_gamma, bn_beta,
                                                         bn_mean, bn_var, Yb);
    cbr0_kernel<<<dim3(DIMC, Bc), 256, 0, stream>>>(x, pc, conv_w, bn_gamma, bn_beta,
                                                    bn_mean, bn_var, y0b, b0);
    seq_kernel<<<dim3(L_, Bc), 256, 0, stream>>>(x, pc, y0b, Yb, seqb, b0);
    // in_proj: xz = seq @ in_proj_w^T
    gemm_kernel<<<dim3((DXZ + 63) / 64, Mci / 64), 256, 0, stream>>>(
        seqb, DMODEL, in_proj_w, DMODEL, xzb, DXZ, Mci, DXZ, DMODEL, 0, nullptr, nullptr, 0);
    // conv1d + silu
    conv1d_kernel<<<dim3((DINNER + 255) / 256, Mci), 256, 0, stream>>>(xzb, conv1d_w, conv1d_b, vb);
    // x_proj: dbl = u @ x_proj_w^T
    gemm_kernel<<<dim3((DBLW + 63) / 64, Mci / 64), 256, 0, stream>>>(
        vb, DINNER, x_proj_w, DINNER, dblb, DBLW, Mci, DBLW, DINNER, 0, nullptr, nullptr, 0);
    // dt_proj + softplus: dt = softplus(dbl[:, :81] @ dt_proj_w^T + b)
    gemm_kernel<<<dim3((DINNER + 63) / 64, Mci / 64), 256, 0, stream>>>(
        dblb, DBLW, dt_proj_w, DTRANK, dtb, DINNER, Mci, DINNER, DTRANK, 1, dt_proj_b, nullptr, 0);
    // scan (overwrites dtb with gated y)
    scan_kernel<<<dim3((DINNER + 255) / 256, Bc), 256, 0, stream>>>(dtb, vb, xzb, dblb, A_log, Dvec);
    // out_proj, transposed write into d_out
    gemm_kernel<<<dim3((DMODEL + 63) / 64, Mci / 64), 256, 0, stream>>>(
        dtb, DINNER, out_proj_w, DINNER, nullptr, 0, Mci, DMODEL, DINNER, 2, nullptr, out, b0);
  }
}

// Round 2
// 6096.626 us; speedup vs baseline: 1.6399x; 1.6399x over previous
//
#include <hip/hip_runtime.h>
#include <hip/hip_bf16.h>
#include <math.h>

#define H_ 16
#define W_ 16
#define L_ 256
#define BATCH 64
#define CIMG 512
#define CPC 256
#define COMB_ 770
#define DIMC 128
#define DMODEL 1282
#define DINNER 2564
#define DXZ 5128
#define DTRANK 81
#define NSTATE 16
#define NPOS 275   // 25 + 81 + 169
#define DBLW 113   // 81 + 16 + 16

#define KP_IN 1312     // 1282 padded to mult of 32
#define KP_OUT 2592    // 2564 padded to mult of 32
#define NPAD_IN 5248   // 5128 padded to mult of 128
#define NPAD_OUT 1408  // 1282 padded to mult of 128

typedef __attribute__((ext_vector_type(8))) short short8;
typedef __attribute__((ext_vector_type(4))) float f32x4;

// ---------------------------------------------------------------------------
// helpers
// ---------------------------------------------------------------------------
__device__ __forceinline__ float comb_val(const float* __restrict__ x,
                                          const float* __restrict__ pc,
                                          int bg, int c, int h, int w) {
  if (c < CIMG)    return x[(((size_t)bg * CIMG + c) << 8) + (h << 4) + w];
  if (c == CIMG)   return -0.3f + 0.04f * (float)w;
  if (c == CIMG+1) return -0.3f + 0.04f * (float)h;
  return pc[bg * CPC + (c - (CIMG + 2))];
}

__device__ __forceinline__ void split_bf16(float v, unsigned short& h, unsigned short& l) {
  __hip_bfloat16 hb = __float2bfloat16(v);
  h = __builtin_bit_cast(unsigned short, hb);
  float r = v - __bfloat162float(hb);
  __hip_bfloat16 lb = __float2bfloat16(r);
  l = __builtin_bit_cast(unsigned short, lb);
}

__device__ __forceinline__ void idx_to_scale(int idx, int& s, int& o, int& p, int& base) {
  if (idx < 25)       { s = 5;  base = 0; }
  else if (idx < 106) { s = 9;  base = 25; }
  else                { s = 13; base = 106; }
  int r = idx - base;
  o = r / s; p = r - o * s;
}

// ---------------------------------------------------------------------------
// W-split: fp32 [N,K] -> bf16 hi/lo [Npad,Kp], zero-padded
// ---------------------------------------------------------------------------
__global__ __launch_bounds__(256) void wsplit_kernel(
    const float* __restrict__ W, int N, int K,
    unsigned short* __restrict__ Wh, unsigned short* __restrict__ Wl, int Kp) {
  int k = blockIdx.x * 256 + threadIdx.x;
  if (k >= Kp) return;
  int n = blockIdx.y;
  float v = (n < N && k < K) ? W[(size_t)n * K + k] : 0.f;
  unsigned short h, l;
  split_bf16(v, h, l);
  Wh[(size_t)n * Kp + k] = h;
  Wl[(size_t)n * Kp + k] = l;
}

// ---------------------------------------------------------------------------
// K1: adaptive-avg-pool of comb for scales {5,9,13} -> P[bl][c][idx(275)]
// ---------------------------------------------------------------------------
__global__ __launch_bounds__(256) void pool_kernel(
    const float* __restrict__ x, const float* __restrict__ pc,
    float* __restrict__ P, int b0) {
  int t = blockIdx.x * 256 + threadIdx.x;
  if (t >= COMB_ * NPOS) return;
  int bl = blockIdx.y;
  int bg = b0 + bl;
  int c = t / NPOS;
  int idx = t - c * NPOS;
  int s, o, p, base; idx_to_scale(idx, s, o, p, base);
  int hs = (o * 16) / s, he = ((o + 1) * 16 + s - 1) / s;
  int ws2 = (p * 16) / s, we = ((p + 1) * 16 + s - 1) / s;
  float sum = 0.f;
  for (int h = hs; h < he; h++)
    for (int w = ws2; w < we; w++)
      sum += comb_val(x, pc, bg, c, h, w);
  P[((size_t)bl * COMB_ + c) * NPOS + idx] = sum / (float)((he - hs) * (we - ws2));
}

// ---------------------------------------------------------------------------
// K2: 1x1 conv + BN + ReLU6 on pooled maps (scales 1..3) -> Y[bl][idx][d]
// ---------------------------------------------------------------------------
__global__ __launch_bounds__(256) void cbr_small_kernel(
    const float* __restrict__ P, const float* __restrict__ conv_w,
    const float* __restrict__ gamma, const float* __restrict__ beta,
    const float* __restrict__ mean, const float* __restrict__ var,
    float* __restrict__ Y) {
  int d = blockIdx.x, bl = blockIdx.y;
  __shared__ float wsm[3 * COMB_];
  for (int e = threadIdx.x; e < 3 * COMB_; e += 256) {
    int i = e / COMB_, c = e - i * COMB_;
    wsm[e] = conv_w[((size_t)(i + 1) * DIMC + d) * COMB_ + c];
  }
  __syncthreads();
  for (int idx = threadIdx.x; idx < NPOS; idx += 256) {
    int i = (idx < 25) ? 1 : (idx < 106 ? 2 : 3);
    const float* wr = &wsm[(i - 1) * COMB_];
    const float* pr = &P[(size_t)bl * COMB_ * NPOS + idx];
    float acc = 0.f;
    for (int c = 0; c < COMB_; c++) acc += wr[c] * pr[(size_t)c * NPOS];
    int bi = i * DIMC + d;
    float inv = rsqrtf(var[bi] + 1e-5f) * gamma[bi];
    float bs = beta[bi] - mean[bi] * inv;
    float v = acc * inv + bs;
    v = fminf(fmaxf(v, 0.f), 6.f);
    Y[((size_t)bl * NPOS + idx) * DIMC + d] = v;
  }
}

// ---------------------------------------------------------------------------
// K3: scale-0 path: CBR at full res then spatial mean -> y0[bl][d]
// ---------------------------------------------------------------------------
__global__ __launch_bounds__(256) void cbr0_kernel(
    const float* __restrict__ x, const float* __restrict__ pc,
    const float* __restrict__ conv_w,
    const float* __restrict__ gamma, const float* __restrict__ beta,
    const float* __restrict__ mean, const float* __restrict__ var,
    float* __restrict__ y0, int b0) {
  int d = blockIdx.x, bl = blockIdx.y, bg = b0 + bl;
  __shared__ float w0[COMB_];
  __shared__ float red[4];
  for (int e = threadIdx.x; e < COMB_; e += 256)
    w0[e] = conv_w[(size_t)d * COMB_ + e];
  __syncthreads();
  int l = threadIdx.x;
  int h = l >> 4, w = l & 15;
  float acc = 0.f;
  for (int c = 0; c < CIMG; c++)
    acc += w0[c] * x[(((size_t)bg * CIMG + c) << 8) + l];
  acc += w0[CIMG]     * (-0.3f + 0.04f * (float)w);
  acc += w0[CIMG + 1] * (-0.3f + 0.04f * (float)h);
  for (int c = 0; c < CPC; c++)
    acc += w0[CIMG + 2 + c] * pc[bg * CPC + c];
  float inv = rsqrtf(var[d] + 1e-5f) * gamma[d];
  float bs = beta[d] - mean[d] * inv;
  float v = fminf(fmaxf(acc * inv + bs, 0.f), 6.f);
  #pragma unroll
  for (int off = 32; off > 0; off >>= 1) v += __shfl_down(v, off);
  if ((threadIdx.x & 63) == 0) red[threadIdx.x >> 6] = v;
  __syncthreads();
  if (threadIdx.x == 0)
    y0[bl * DIMC + d] = (red[0] + red[1] + red[2] + red[3]) * (1.f / 256.f);
}

// ---------------------------------------------------------------------------
// K4: assemble seq as split bf16 [bl*L][KP_IN] hi/lo, zero-padded cols
// ---------------------------------------------------------------------------
__global__ __launch_bounds__(256) void seq_kernel(
    const float* __restrict__ x, const float* __restrict__ pc,
    const float* __restrict__ y0, const float* __restrict__ Y,
    unsigned short* __restrict__ seqh, unsigned short* __restrict__ seql, int b0) {
  int l = blockIdx.x, bl = blockIdx.y, bg = b0 + bl;
  int h = l >> 4, w = l & 15;
  size_t rb = ((size_t)bl * L_ + l) * KP_IN;
  for (int c = threadIdx.x; c < KP_IN; c += 256) {
    float v;
    if (c < COMB_) {
      v = comb_val(x, pc, bg, c, h, w);
    } else if (c < COMB_ + DIMC) {
      v = y0[bl * DIMC + (c - COMB_)];
    } else if (c < DMODEL) {
      int cc = c - (COMB_ + DIMC);
      int si = cc >> 7;
      int d = cc & 127;
      int s    = (si == 0) ? 5 : ((si == 1) ? 9 : 13);
      int base = (si == 0) ? 0 : ((si == 1) ? 25 : 106);
      float srch = (h + 0.5f) * (float)s * (1.f / 16.f) - 0.5f;
      srch = fminf(fmaxf(srch, 0.f), (float)(s - 1));
      int o0 = (int)floorf(srch);
      float fh = srch - (float)o0;
      int o1 = min(o0 + 1, s - 1);
      float srcw = (w + 0.5f) * (float)s * (1.f / 16.f) - 0.5f;
      srcw = fminf(fmaxf(srcw, 0.f), (float)(s - 1));
      int p0 = (int)floorf(srcw);
      float fw = srcw - (float)p0;
      int p1 = min(p0 + 1, s - 1);
      const float* Yb = &Y[((size_t)bl * NPOS + base) * DIMC + d];
      float v00 = Yb[(size_t)(o0 * s + p0) * DIMC];
      float v01 = Yb[(size_t)(o0 * s + p1) * DIMC];
      float v10 = Yb[(size_t)(o1 * s + p0) * DIMC];
      float v11 = Yb[(size_t)(o1 * s + p1) * DIMC];
      v = (1.f - fh) * ((1.f - fw) * v00 + fw * v01)
        +        fh  * ((1.f - fw) * v10 + fw * v11);
    } else {
      v = 0.f;
    }
    unsigned short hh, ll;
    split_bf16(v, hh, ll);
    seqh[rb + c] = hh;
    seql[rb + c] = ll;
  }
}

// ---------------------------------------------------------------------------
// K5: split-bf16 MFMA GEMM.  C[M,N] = (Ah+Al)[M,Kp] * (Bh+Bl)[Npad,Kp]^T
// 3 phases: Ah*Bh + Ah*Bl + Al*Bh. 128x128 tile, BK=32, 4 waves, 16x16x32.
// mode 0: C[gm*ldc+gn] = v.  mode 2: out[b][gn][l] transposed (vectorized).
// ---------------------------------------------------------------------------
__global__ __launch_bounds__(256) void mfma_gemm_kernel(
    const unsigned short* __restrict__ Ah, const unsigned short* __restrict__ Al, int Kp,
    const unsigned short* __restrict__ Bh, const unsigned short* __restrict__ Bl,
    float* __restrict__ C, int ldc, int M, int N, int mode,
    float* __restrict__ outT, int b0) {
  __shared__ __align__(16) unsigned short As[128 * 32];
  __shared__ __align__(16) unsigned short Bs[128 * 32];
  int tid = threadIdx.x;
  int lane = tid & 63;
  int wave = tid >> 6;
  int m0 = blockIdx.y << 7, n0 = blockIdx.x << 7;
  int wm = (wave & 1) << 6, wn = (wave >> 1) << 6;
  f32x4 acc[4][4] = {};
  int mrow = lane & 15, koff = (lane >> 4) << 3;

  for (int phase = 0; phase < 3; phase++) {
    const unsigned short* Ap = (phase < 2) ? Ah : Al;
    const unsigned short* Bp = (phase == 1) ? Bl : Bh;
    for (int k0 = 0; k0 < Kp; k0 += 32) {
      #pragma unroll
      for (int j = 0; j < 2; j++) {
        int c = (j << 8) + tid;
        int r = c >> 2, kc = (c & 3) << 3;
        __builtin_amdgcn_global_load_lds(
            (const __attribute__((address_space(1))) unsigned int*)(Ap + (size_t)(m0 + r) * Kp + k0 + kc),
            (__attribute__((address_space(3))) unsigned int*)(&As[c << 3]), 16, 0, 0);
        __builtin_amdgcn_global_load_lds(
            (const __attribute__((address_space(1))) unsigned int*)(Bp + (size_t)(n0 + r) * Kp + k0 + kc),
            (__attribute__((address_space(3))) unsigned int*)(&Bs[c << 3]), 16, 0, 0);
      }
      __syncthreads();
      short8 a[4], b[4];
      #pragma unroll
      for (int i = 0; i < 4; i++)
        a[i] = *(const short8*)&As[(wm + (i << 4) + mrow) * 32 + koff];
      #pragma unroll
      for (int j = 0; j < 4; j++)
        b[j] = *(const short8*)&Bs[(wn + (j << 4) + mrow) * 32 + koff];
      #pragma unroll
      for (int i = 0; i < 4; i++)
        #pragma unroll
        for (int j = 0; j < 4; j++)
          acc[i][j] = __builtin_amdgcn_mfma_f32_16x16x32_bf16(a[i], b[j], acc[i][j], 0, 0, 0);
      __syncthreads();
    }
  }

  int n_l = lane & 15, m_l = (lane >> 4) << 2;
  #pragma unroll
  for (int i = 0; i < 4; i++) {
    int gm0 = m0 + wm + (i << 4) + m_l;
    #pragma unroll
    for (int j = 0; j < 4; j++) {
      int gn = n0 + wn + (j << 4) + n_l;
      if (gn >= N) continue;
      if (mode == 2) {
        int bb = b0 + (gm0 >> 8), l0 = gm0 & 255;
        *(f32x4*)&outT[(((size_t)bb * DMODEL + gn) << 8) + l0] = acc[i][j];
      } else {
        #pragma unroll
        for (int r = 0; r < 4; r++)
          C[(size_t)(gm0 + r) * ldc + gn] = acc[i][j][r];
      }
    }
  }
}

// ---------------------------------------------------------------------------
// K5b: generic fp32 GEMM (kept for x_proj, dt_proj)
// ---------------------------------------------------------------------------
__global__ __launch_bounds__(256) void gemm_kernel(
    const float* __restrict__ A, int lda,
    const float* __restrict__ Wt, int ldw,
    float* __restrict__ C, int ldc,
    int M, int N, int K, int mode,
    const float* __restrict__ bias) {
  __shared__ float As[16][68];
  __shared__ float Ws[16][68];
  int tid = threadIdx.x;
  int tx = tid & 15, ty = tid >> 4;
  int m0 = blockIdx.y << 6, n0 = blockIdx.x << 6;
  float acc[4][4] = {{0.f}};
  for (int k0 = 0; k0 < K; k0 += 16) {
    #pragma unroll
    for (int i = 0; i < 4; i++) {
      int e = tid + (i << 8);
      int mm = e >> 4, kk = e & 15;
      int gm = m0 + mm, gk = k0 + kk;
      As[kk][mm] = (gm < M && gk < K) ? A[(size_t)gm * lda + gk] : 0.f;
      int gn = n0 + mm;
      Ws[kk][mm] = (gn < N && gk < K) ? Wt[(size_t)gn * ldw + gk] : 0.f;
    }
    __syncthreads();
    #pragma unroll
    for (int kk = 0; kk < 16; kk++) {
      float a[4], b[4];
      #pragma unroll
      for (int i = 0; i < 4; i++) a[i] = As[kk][(ty << 2) + i];
      #pragma unroll
      for (int j = 0; j < 4; j++) b[j] = Ws[kk][(tx << 2) + j];
      #pragma unroll
      for (int i = 0; i < 4; i++)
        #pragma unroll
        for (int j = 0; j < 4; j++) acc[i][j] += a[i] * b[j];
    }
    __syncthreads();
  }
  #pragma unroll
  for (int i = 0; i < 4; i++) {
    int gm = m0 + (ty << 2) + i;
    if (gm >= M) continue;
    #pragma unroll
    for (int j = 0; j < 4; j++) {
      int gn = n0 + (tx << 2) + j;
      if (gn >= N) continue;
      float vv = acc[i][j];
      if (mode == 1) {
        vv += bias[gn];
        vv = (vv > 20.f) ? vv : log1pf(expf(vv));
      }
      C[(size_t)gm * ldc + gn] = vv;
    }
  }
}

// ---------------------------------------------------------------------------
// K6: depthwise causal conv1d (k=4) + bias + silu
// ---------------------------------------------------------------------------
__global__ __launch_bounds__(256) void conv1d_kernel(
    const float* __restrict__ xz, const float* __restrict__ cw,
    const float* __restrict__ cb, float* __restrict__ v) {
  int d = blockIdx.x * 256 + threadIdx.x;
  if (d >= DINNER) return;
  int m = blockIdx.y;
  int l = m & 255;
  float acc = cb[d];
  #pragma unroll
  for (int j = 0; j < 4; j++) {
    int ll = l - 3 + j;
    if (ll >= 0) acc += cw[d * 4 + j] * xz[(size_t)(m - 3 + j) * DXZ + d];
  }
  v[(size_t)m * DINNER + d] = acc / (1.f + __expf(-acc));
}

// ---------------------------------------------------------------------------
// K7: selective scan. writes gated y as split bf16 [m][KP_OUT]
// ---------------------------------------------------------------------------
__global__ __launch_bounds__(256) void scan_kernel(
    const float* __restrict__ dtv,
    const float* __restrict__ v, const float* __restrict__ xz,
    const float* __restrict__ dbl, const float* __restrict__ A_log,
    const float* __restrict__ Dv,
    unsigned short* __restrict__ yh, unsigned short* __restrict__ yl) {
  int d = blockIdx.x * 256 + threadIdx.x;
  if (d >= KP_OUT) return;
  int bl = blockIdx.y;
  if (d >= DINNER) {   // zero-fill K padding
    for (int l = 0; l < L_; l++) {
      size_t m = (size_t)bl * L_ + l;
      yh[m * KP_OUT + d] = 0;
      yl[m * KP_OUT + d] = 0;
    }
    return;
  }
  float A[NSTATE], hst[NSTATE];
  #pragma unroll
  for (int n = 0; n < NSTATE; n++) {
    A[n] = -__expf(A_log[d * NSTATE + n]);
    hst[n] = 0.f;
  }
  float Dd = Dv[d];
  for (int l = 0; l < L_; l++) {
    size_t m = (size_t)bl * L_ + l;
    float dt = dtv[m * DINNER + d];
    float uu = v[m * DINNER + d];
    float zz = xz[m * DXZ + DINNER + d];
    const float* bc = &dbl[m * DBLW];
    float du = dt * uu;
    float y = 0.f;
    #pragma unroll
    for (int n = 0; n < NSTATE; n++) {
      float dA = __expf(dt * A[n]);
      hst[n] = dA * hst[n] + du * bc[DTRANK + n];
      y += hst[n] * bc[DTRANK + NSTATE + n];
    }
    float val = (y + uu * Dd) * (zz / (1.f + __expf(-zz)));
    unsigned short hh, ll;
    split_bf16(val, hh, ll);
    yh[m * KP_OUT + d] = hh;
    yl[m * KP_OUT + d] = ll;
  }
}

// ---------------------------------------------------------------------------
// launch
// ---------------------------------------------------------------------------
extern "C" void kernel_launch(void* const* d_in, const int* in_sizes, int n_in,
                              void* d_out, int out_size, void* d_ws, size_t ws_size,
                              hipStream_t stream) {
  const float* x         = (const float*)d_in[0];
  const float* pc        = (const float*)d_in[1];
  const float* conv_w    = (const float*)d_in[2];
  const float* bn_gamma  = (const float*)d_in[3];
  const float* bn_beta   = (const float*)d_in[4];
  const float* bn_mean   = (const float*)d_in[5];
  const float* bn_var    = (const float*)d_in[6];
  const float* in_proj_w = (const float*)d_in[7];
  const float* conv1d_w  = (const float*)d_in[8];
  const float* conv1d_b  = (const float*)d_in[9];
  const float* x_proj_w  = (const float*)d_in[10];
  const float* dt_proj_w = (const float*)d_in[11];
  const float* dt_proj_b = (const float*)d_in[12];
  const float* A_log     = (const float*)d_in[13];
  const float* Dvec      = (const float*)d_in[14];
  const float* out_proj_w= (const float*)d_in[15];
  float* out = (float*)d_out;

  auto al = [](size_t vv) { return (vv + 255) & ~(size_t)255; };

  // fixed (per-call) weight split buffers
  size_t w_in_sz  = al((size_t)NPAD_IN * KP_IN * 2);
  size_t w_out_sz = al((size_t)NPAD_OUT * KP_OUT * 2);
  size_t fixed = 2 * w_in_sz + 2 * w_out_sz;

  auto calc = [&](int bc) -> size_t {
    size_t Mc = (size_t)bc * L_;
    size_t s = fixed;
    s += 2 * al(Mc * KP_IN * 2);              // seq hi/lo
    s += al((size_t)bc * COMB_ * NPOS * 4);   // P
    s += al((size_t)bc * NPOS * DIMC * 4);    // Y
    s += al((size_t)bc * DIMC * 4);           // y0
    s += al(Mc * DXZ * 4);                    // xz
    s += al(Mc * DINNER * 4);                 // v
    s += al(Mc * DBLW * 4);                   // dbl
    s += al(Mc * DINNER * 4);                 // dt
    s += 2 * al(Mc * KP_OUT * 2);             // y hi/lo
    return s;
  };
  int Bc = 64;
  while (Bc > 1 && calc(Bc) > ws_size) Bc >>= 1;

  size_t Mc = (size_t)Bc * L_;
  char* base = (char*)d_ws;
  size_t off = 0;
  unsigned short* Wih = (unsigned short*)(base + off); off += w_in_sz;
  unsigned short* Wil = (unsigned short*)(base + off); off += w_in_sz;
  unsigned short* Woh = (unsigned short*)(base + off); off += w_out_sz;
  unsigned short* Wol = (unsigned short*)(base + off); off += w_out_sz;
  unsigned short* seqh = (unsigned short*)(base + off); off += al(Mc * KP_IN * 2);
  unsigned short* seql = (unsigned short*)(base + off); off += al(Mc * KP_IN * 2);
  float* Pb   = (float*)(base + off); off += al((size_t)Bc * COMB_ * NPOS * 4);
  float* Yb   = (float*)(base + off); off += al((size_t)Bc * NPOS * DIMC * 4);
  float* y0b  = (float*)(base + off); off += al((size_t)Bc * DIMC * 4);
  float* xzb  = (float*)(base + off); off += al(Mc * DXZ * 4);
  float* vb   = (float*)(base + off); off += al(Mc * DINNER * 4);
  float* dblb = (float*)(base + off); off += al(Mc * DBLW * 4);
  float* dtb  = (float*)(base + off); off += al(Mc * DINNER * 4);
  unsigned short* yhb = (unsigned short*)(base + off); off += al(Mc * KP_OUT * 2);
  unsigned short* ylb = (unsigned short*)(base + off); off += al(Mc * KP_OUT * 2);

  // split weights (once per call)
  wsplit_kernel<<<dim3((KP_IN + 255) / 256, NPAD_IN), 256, 0, stream>>>(
      in_proj_w, DXZ, DMODEL, Wih, Wil, KP_IN);
  wsplit_kernel<<<dim3((KP_OUT + 255) / 256, NPAD_OUT), 256, 0, stream>>>(
      out_proj_w, DMODEL, DINNER, Woh, Wol, KP_OUT);

  for (int b0 = 0; b0 < BATCH; b0 += Bc) {
    int Mci = Bc * L_;
    // PPM
    pool_kernel<<<dim3((COMB_ * NPOS + 255) / 256, Bc), 256, 0, stream>>>(x, pc, Pb, b0);
    cbr_small_kernel<<<dim3(DIMC, Bc), 256, 0, stream>>>(Pb, conv_w, bn_gamma, bn_beta,
                                                         bn_mean, bn_var, Yb);
    cbr0_kernel<<<dim3(DIMC, Bc), 256, 0, stream>>>(x, pc, conv_w, bn_gamma, bn_beta,
                                                    bn_mean, bn_var, y0b, b0);
    seq_kernel<<<dim3(L_, Bc), 256, 0, stream>>>(x, pc, y0b, Yb, seqh, seql, b0);
    // in_proj: xz = seq @ in_proj_w^T  (split-bf16 MFMA)
    mfma_gemm_kernel<<<dim3(NPAD_IN / 128, Mci / 128), 256, 0, stream>>>(
        seqh, seql, KP_IN, Wih, Wil, xzb, DXZ, Mci, DXZ, 0, nullptr, 0);
    // conv1d + silu
    conv1d_kernel<<<dim3((DINNER + 255) / 256, Mci), 256, 0, stream>>>(xzb, conv1d_w, conv1d_b, vb);
    // x_proj (fp32)
    gemm_kernel<<<dim3((DBLW + 63) / 64, Mci / 64), 256, 0, stream>>>(
        vb, DINNER, x_proj_w, DINNER, dblb, DBLW, Mci, DBLW, DINNER, 0, nullptr);
    // dt_proj + softplus (fp32)
    gemm_kernel<<<dim3((DINNER + 63) / 64, Mci / 64), 256, 0, stream>>>(
        dblb, DBLW, dt_proj_w, DTRANK, dtb, DINNER, Mci, DINNER, DTRANK, 1, dt_proj_b);
    // scan -> split-bf16 y
    scan_kernel<<<dim3((KP_OUT + 255) / 256, Bc), 256, 0, stream>>>(
        dtb, vb, xzb, dblb, A_log, Dvec, yhb, ylb);
    // out_proj (split-bf16 MFMA), transposed write into d_out
    mfma_gemm_kernel<<<dim3(NPAD_OUT / 128, Mci / 128), 256, 0, stream>>>(
        yhb, ylb, KP_OUT, Woh, Wol, nullptr, 0, Mci, DMODEL, 2, out, b0);
  }
}

// Round 3
// 4668.518 us; speedup vs baseline: 2.1416x; 1.3059x over previous
//
#include <hip/hip_runtime.h>
#include <hip/hip_bf16.h>
#include <math.h>

#define H_ 16
#define W_ 16
#define L_ 256
#define BATCH 64
#define CIMG 512
#define CPC 256
#define COMB_ 770
#define DIMC 128
#define DMODEL 1282
#define DINNER 2564
#define DXZ 5128
#define DTRANK 81
#define NSTATE 16
#define NPOS 275   // 25 + 81 + 169
#define DBLP 128   // padded stride of dbl rows (81 dt | 16 B | 16 C | pad)

#define KP_IN 1312     // 1282 padded to mult of 32
#define KP_OUT 2592    // 2564 padded to mult of 32
#define KP_DT 96       // 81 padded to mult of 32
#define NPAD_IN 5248   // 5128 padded to mult of 128
#define NPAD_OUT 1408  // 1282 padded to mult of 128
#define NPAD_X 128     // 113 padded
#define NPAD_DT 2688   // 2564 padded

typedef __attribute__((ext_vector_type(8))) short short8;
typedef __attribute__((ext_vector_type(4))) float f32x4;

// ---------------------------------------------------------------------------
// helpers
// ---------------------------------------------------------------------------
__device__ __forceinline__ float comb_val(const float* __restrict__ x,
                                          const float* __restrict__ pc,
                                          int bg, int c, int h, int w) {
  if (c < CIMG)    return x[(((size_t)bg * CIMG + c) << 8) + (h << 4) + w];
  if (c == CIMG)   return -0.3f + 0.04f * (float)w;
  if (c == CIMG+1) return -0.3f + 0.04f * (float)h;
  return pc[bg * CPC + (c - (CIMG + 2))];
}

__device__ __forceinline__ void split_bf16(float v, unsigned short& h, unsigned short& l) {
  __hip_bfloat16 hb = __float2bfloat16(v);
  h = __builtin_bit_cast(unsigned short, hb);
  float r = v - __bfloat162float(hb);
  __hip_bfloat16 lb = __float2bfloat16(r);
  l = __builtin_bit_cast(unsigned short, lb);
}

__device__ __forceinline__ float bf16_val(unsigned short u) {
  return __bfloat162float(__builtin_bit_cast(__hip_bfloat16, u));
}

__device__ __forceinline__ void idx_to_scale(int idx, int& s, int& o, int& p, int& base) {
  if (idx < 25)       { s = 5;  base = 0; }
  else if (idx < 106) { s = 9;  base = 25; }
  else                { s = 13; base = 106; }
  int r = idx - base;
  o = r / s; p = r - o * s;
}

// ---------------------------------------------------------------------------
// W-split: fp32 [N,K] -> bf16 hi/lo [Npad,Kp], zero-padded
// ---------------------------------------------------------------------------
__global__ __launch_bounds__(256) void wsplit_kernel(
    const float* __restrict__ W, int N, int K,
    unsigned short* __restrict__ Wh, unsigned short* __restrict__ Wl, int Kp) {
  int k = blockIdx.x * 256 + threadIdx.x;
  if (k >= Kp) return;
  int n = blockIdx.y;
  float v = (n < N && k < K) ? W[(size_t)n * K + k] : 0.f;
  unsigned short h, l;
  split_bf16(v, h, l);
  Wh[(size_t)n * Kp + k] = h;
  Wl[(size_t)n * Kp + k] = l;
}

// ---------------------------------------------------------------------------
// K1: adaptive-avg-pool of comb for scales {5,9,13} -> P[bl][c][idx(275)]
// ---------------------------------------------------------------------------
__global__ __launch_bounds__(256) void pool_kernel(
    const float* __restrict__ x, const float* __restrict__ pc,
    float* __restrict__ P, int b0) {
  int t = blockIdx.x * 256 + threadIdx.x;
  if (t >= COMB_ * NPOS) return;
  int bl = blockIdx.y;
  int bg = b0 + bl;
  int c = t / NPOS;
  int idx = t - c * NPOS;
  int s, o, p, base; idx_to_scale(idx, s, o, p, base);
  int hs = (o * 16) / s, he = ((o + 1) * 16 + s - 1) / s;
  int ws2 = (p * 16) / s, we = ((p + 1) * 16 + s - 1) / s;
  float sum = 0.f;
  for (int h = hs; h < he; h++)
    for (int w = ws2; w < we; w++)
      sum += comb_val(x, pc, bg, c, h, w);
  P[((size_t)bl * COMB_ + c) * NPOS + idx] = sum / (float)((he - hs) * (we - ws2));
}

// ---------------------------------------------------------------------------
// K2: 1x1 conv + BN + ReLU6 on pooled maps (scales 1..3) -> Y[bl][idx][d]
// ---------------------------------------------------------------------------
__global__ __launch_bounds__(256) void cbr_small_kernel(
    const float* __restrict__ P, const float* __restrict__ conv_w,
    const float* __restrict__ gamma, const float* __restrict__ beta,
    const float* __restrict__ mean, const float* __restrict__ var,
    float* __restrict__ Y) {
  int d = blockIdx.x, bl = blockIdx.y;
  __shared__ float wsm[3 * COMB_];
  for (int e = threadIdx.x; e < 3 * COMB_; e += 256) {
    int i = e / COMB_, c = e - i * COMB_;
    wsm[e] = conv_w[((size_t)(i + 1) * DIMC + d) * COMB_ + c];
  }
  __syncthreads();
  for (int idx = threadIdx.x; idx < NPOS; idx += 256) {
    int i = (idx < 25) ? 1 : (idx < 106 ? 2 : 3);
    const float* wr = &wsm[(i - 1) * COMB_];
    const float* pr = &P[(size_t)bl * COMB_ * NPOS + idx];
    float acc = 0.f;
    for (int c = 0; c < COMB_; c++) acc += wr[c] * pr[(size_t)c * NPOS];
    int bi = i * DIMC + d;
    float inv = rsqrtf(var[bi] + 1e-5f) * gamma[bi];
    float bs = beta[bi] - mean[bi] * inv;
    float v = acc * inv + bs;
    v = fminf(fmaxf(v, 0.f), 6.f);
    Y[((size_t)bl * NPOS + idx) * DIMC + d] = v;
  }
}

// ---------------------------------------------------------------------------
// K3: scale-0 path: CBR at full res then spatial mean -> y0[bl][d]
// ---------------------------------------------------------------------------
__global__ __launch_bounds__(256) void cbr0_kernel(
    const float* __restrict__ x, const float* __restrict__ pc,
    const float* __restrict__ conv_w,
    const float* __restrict__ gamma, const float* __restrict__ beta,
    const float* __restrict__ mean, const float* __restrict__ var,
    float* __restrict__ y0, int b0) {
  int d = blockIdx.x, bl = blockIdx.y, bg = b0 + bl;
  __shared__ float w0[COMB_];
  __shared__ float red[4];
  for (int e = threadIdx.x; e < COMB_; e += 256)
    w0[e] = conv_w[(size_t)d * COMB_ + e];
  __syncthreads();
  int l = threadIdx.x;
  int h = l >> 4, w = l & 15;
  float acc = 0.f;
  for (int c = 0; c < CIMG; c++)
    acc += w0[c] * x[(((size_t)bg * CIMG + c) << 8) + l];
  acc += w0[CIMG]     * (-0.3f + 0.04f * (float)w);
  acc += w0[CIMG + 1] * (-0.3f + 0.04f * (float)h);
  for (int c = 0; c < CPC; c++)
    acc += w0[CIMG + 2 + c] * pc[bg * CPC + c];
  float inv = rsqrtf(var[d] + 1e-5f) * gamma[d];
  float bs = beta[d] - mean[d] * inv;
  float v = fminf(fmaxf(acc * inv + bs, 0.f), 6.f);
  #pragma unroll
  for (int off = 32; off > 0; off >>= 1) v += __shfl_down(v, off);
  if ((threadIdx.x & 63) == 0) red[threadIdx.x >> 6] = v;
  __syncthreads();
  if (threadIdx.x == 0)
    y0[bl * DIMC + d] = (red[0] + red[1] + red[2] + red[3]) * (1.f / 256.f);
}

// ---------------------------------------------------------------------------
// K4: assemble seq as split bf16 [bl*L][KP_IN] hi/lo, zero-padded cols
// ---------------------------------------------------------------------------
__global__ __launch_bounds__(256) void seq_kernel(
    const float* __restrict__ x, const float* __restrict__ pc,
    const float* __restrict__ y0, const float* __restrict__ Y,
    unsigned short* __restrict__ seqh, unsigned short* __restrict__ seql, int b0) {
  int l = blockIdx.x, bl = blockIdx.y, bg = b0 + bl;
  int h = l >> 4, w = l & 15;
  size_t rb = ((size_t)bl * L_ + l) * KP_IN;
  for (int c = threadIdx.x; c < KP_IN; c += 256) {
    float v;
    if (c < COMB_) {
      v = comb_val(x, pc, bg, c, h, w);
    } else if (c < COMB_ + DIMC) {
      v = y0[bl * DIMC + (c - COMB_)];
    } else if (c < DMODEL) {
      int cc = c - (COMB_ + DIMC);
      int si = cc >> 7;
      int d = cc & 127;
      int s    = (si == 0) ? 5 : ((si == 1) ? 9 : 13);
      int base = (si == 0) ? 0 : ((si == 1) ? 25 : 106);
      float srch = (h + 0.5f) * (float)s * (1.f / 16.f) - 0.5f;
      srch = fminf(fmaxf(srch, 0.f), (float)(s - 1));
      int o0 = (int)floorf(srch);
      float fh = srch - (float)o0;
      int o1 = min(o0 + 1, s - 1);
      float srcw = (w + 0.5f) * (float)s * (1.f / 16.f) - 0.5f;
      srcw = fminf(fmaxf(srcw, 0.f), (float)(s - 1));
      int p0 = (int)floorf(srcw);
      float fw = srcw - (float)p0;
      int p1 = min(p0 + 1, s - 1);
      const float* Yb = &Y[((size_t)bl * NPOS + base) * DIMC + d];
      float v00 = Yb[(size_t)(o0 * s + p0) * DIMC];
      float v01 = Yb[(size_t)(o0 * s + p1) * DIMC];
      float v10 = Yb[(size_t)(o1 * s + p0) * DIMC];
      float v11 = Yb[(size_t)(o1 * s + p1) * DIMC];
      v = (1.f - fh) * ((1.f - fw) * v00 + fw * v01)
        +        fh  * ((1.f - fw) * v10 + fw * v11);
    } else {
      v = 0.f;
    }
    unsigned short hh, ll;
    split_bf16(v, hh, ll);
    seqh[rb + c] = hh;
    seql[rb + c] = ll;
  }
}

// ---------------------------------------------------------------------------
// K5: split-bf16 MFMA GEMM.  C[M,N] = (Ah+Al)[M,Kp] * (Bh+Bl)[Npad,Kp]^T
// 3 phases: Ah*Bh + Ah*Bl + Al*Bh. 128x128 tile, BK=32, 4 waves, 16x16x32.
// mode 0: plain store. mode 1: +bias[n], softplus. mode 2: out[b][gn][l].
// ---------------------------------------------------------------------------
__global__ __launch_bounds__(256) void mfma_gemm_kernel(
    const unsigned short* __restrict__ Ah, const unsigned short* __restrict__ Al, int Kp,
    const unsigned short* __restrict__ Bh, const unsigned short* __restrict__ Bl,
    float* __restrict__ C, int ldc, int M, int N, int mode,
    const float* __restrict__ bias,
    float* __restrict__ outT, int b0) {
  __shared__ __align__(16) unsigned short As[128 * 32];
  __shared__ __align__(16) unsigned short Bs[128 * 32];
  int tid = threadIdx.x;
  int lane = tid & 63;
  int wave = tid >> 6;
  int m0 = blockIdx.y << 7, n0 = blockIdx.x << 7;
  int wm = (wave & 1) << 6, wn = (wave >> 1) << 6;
  f32x4 acc[4][4] = {};
  int mrow = lane & 15, koff = (lane >> 4) << 3;

  for (int phase = 0; phase < 3; phase++) {
    const unsigned short* Ap = (phase < 2) ? Ah : Al;
    const unsigned short* Bp = (phase == 1) ? Bl : Bh;
    for (int k0 = 0; k0 < Kp; k0 += 32) {
      #pragma unroll
      for (int j = 0; j < 2; j++) {
        int c = (j << 8) + tid;
        int r = c >> 2, kc = (c & 3) << 3;
        __builtin_amdgcn_global_load_lds(
            (const __attribute__((address_space(1))) unsigned int*)(Ap + (size_t)(m0 + r) * Kp + k0 + kc),
            (__attribute__((address_space(3))) unsigned int*)(&As[c << 3]), 16, 0, 0);
        __builtin_amdgcn_global_load_lds(
            (const __attribute__((address_space(1))) unsigned int*)(Bp + (size_t)(n0 + r) * Kp + k0 + kc),
            (__attribute__((address_space(3))) unsigned int*)(&Bs[c << 3]), 16, 0, 0);
      }
      __syncthreads();
      short8 a[4], b[4];
      #pragma unroll
      for (int i = 0; i < 4; i++)
        a[i] = *(const short8*)&As[(wm + (i << 4) + mrow) * 32 + koff];
      #pragma unroll
      for (int j = 0; j < 4; j++)
        b[j] = *(const short8*)&Bs[(wn + (j << 4) + mrow) * 32 + koff];
      #pragma unroll
      for (int i = 0; i < 4; i++)
        #pragma unroll
        for (int j = 0; j < 4; j++)
          acc[i][j] = __builtin_amdgcn_mfma_f32_16x16x32_bf16(a[i], b[j], acc[i][j], 0, 0, 0);
      __syncthreads();
    }
  }

  int n_l = lane & 15, m_l = (lane >> 4) << 2;
  #pragma unroll
  for (int i = 0; i < 4; i++) {
    int gm0 = m0 + wm + (i << 4) + m_l;
    #pragma unroll
    for (int j = 0; j < 4; j++) {
      int gn = n0 + wn + (j << 4) + n_l;
      if (gn >= N) continue;
      if (mode == 2) {
        int bb = b0 + (gm0 >> 8), l0 = gm0 & 255;
        *(f32x4*)&outT[(((size_t)bb * DMODEL + gn) << 8) + l0] = acc[i][j];
      } else if (mode == 1) {
        float bv = bias[gn];
        #pragma unroll
        for (int r = 0; r < 4; r++) {
          float vv = acc[i][j][r] + bv;
          vv = (vv > 20.f) ? vv : log1pf(expf(vv));
          C[(size_t)(gm0 + r) * ldc + gn] = vv;
        }
      } else {
        #pragma unroll
        for (int r = 0; r < 4; r++)
          C[(size_t)(gm0 + r) * ldc + gn] = acc[i][j][r];
      }
    }
  }
}

// ---------------------------------------------------------------------------
// K6: depthwise causal conv1d (k=4) + bias + silu -> split bf16 u [m][KP_OUT]
// ---------------------------------------------------------------------------
__global__ __launch_bounds__(256) void conv1d_kernel(
    const float* __restrict__ xz, const float* __restrict__ cw,
    const float* __restrict__ cb,
    unsigned short* __restrict__ vh, unsigned short* __restrict__ vl) {
  int d = blockIdx.x * 256 + threadIdx.x;
  if (d >= KP_OUT) return;
  int m = blockIdx.y;
  size_t o = (size_t)m * KP_OUT + d;
  if (d >= DINNER) { vh[o] = 0; vl[o] = 0; return; }
  int l = m & 255;
  float acc = cb[d];
  #pragma unroll
  for (int j = 0; j < 4; j++) {
    int ll = l - 3 + j;
    if (ll >= 0) acc += cw[d * 4 + j] * xz[(size_t)(m - 3 + j) * DXZ + d];
  }
  float s = acc / (1.f + __expf(-acc));
  unsigned short hh, llv;
  split_bf16(s, hh, llv);
  vh[o] = hh; vl[o] = llv;
}

// ---------------------------------------------------------------------------
// K6b: split dt columns of dbl (fp32, stride DBLP) -> dth/dtl [m][KP_DT]
// ---------------------------------------------------------------------------
__global__ __launch_bounds__(256) void split_dt_kernel(
    const float* __restrict__ dbl,
    unsigned short* __restrict__ dth, unsigned short* __restrict__ dtl, int M) {
  int t = blockIdx.x * 256 + threadIdx.x;
  if (t >= M * KP_DT) return;
  int m = t / KP_DT, k = t - m * KP_DT;
  float v = (k < DTRANK) ? dbl[(size_t)m * DBLP + k] : 0.f;
  unsigned short h, l;
  split_bf16(v, h, l);
  dth[t] = h; dtl[t] = l;
}

// ---------------------------------------------------------------------------
// K7: selective scan. u from split bf16; writes gated y as split bf16
// ---------------------------------------------------------------------------
__global__ __launch_bounds__(256) void scan_kernel(
    const float* __restrict__ dtv,
    const unsigned short* __restrict__ vh, const unsigned short* __restrict__ vl,
    const float* __restrict__ xz,
    const float* __restrict__ dbl, const float* __restrict__ A_log,
    const float* __restrict__ Dv,
    unsigned short* __restrict__ yh, unsigned short* __restrict__ yl) {
  int d = blockIdx.x * 256 + threadIdx.x;
  if (d >= KP_OUT) return;
  int bl = blockIdx.y;
  if (d >= DINNER) {   // zero-fill K padding
    for (int l = 0; l < L_; l++) {
      size_t m = (size_t)bl * L_ + l;
      yh[m * KP_OUT + d] = 0;
      yl[m * KP_OUT + d] = 0;
    }
    return;
  }
  float A[NSTATE], hst[NSTATE];
  #pragma unroll
  for (int n = 0; n < NSTATE; n++) {
    A[n] = -__expf(A_log[d * NSTATE + n]);
    hst[n] = 0.f;
  }
  float Dd = Dv[d];
  for (int l = 0; l < L_; l++) {
    size_t m = (size_t)bl * L_ + l;
    float dt = dtv[m * DINNER + d];
    float uu = bf16_val(vh[m * KP_OUT + d]) + bf16_val(vl[m * KP_OUT + d]);
    float zz = xz[m * DXZ + DINNER + d];
    const float* bc = &dbl[m * DBLP];
    float du = dt * uu;
    float y = 0.f;
    #pragma unroll
    for (int n = 0; n < NSTATE; n++) {
      float dA = __expf(dt * A[n]);
      hst[n] = dA * hst[n] + du * bc[DTRANK + n];
      y += hst[n] * bc[DTRANK + NSTATE + n];
    }
    float val = (y + uu * Dd) * (zz / (1.f + __expf(-zz)));
    unsigned short hh, ll;
    split_bf16(val, hh, ll);
    yh[m * KP_OUT + d] = hh;
    yl[m * KP_OUT + d] = ll;
  }
}

// ---------------------------------------------------------------------------
// launch
// ---------------------------------------------------------------------------
extern "C" void kernel_launch(void* const* d_in, const int* in_sizes, int n_in,
                              void* d_out, int out_size, void* d_ws, size_t ws_size,
                              hipStream_t stream) {
  const float* x         = (const float*)d_in[0];
  const float* pc        = (const float*)d_in[1];
  const float* conv_w    = (const float*)d_in[2];
  const float* bn_gamma  = (const float*)d_in[3];
  const float* bn_beta   = (const float*)d_in[4];
  const float* bn_mean   = (const float*)d_in[5];
  const float* bn_var    = (const float*)d_in[6];
  const float* in_proj_w = (const float*)d_in[7];
  const float* conv1d_w  = (const float*)d_in[8];
  const float* conv1d_b  = (const float*)d_in[9];
  const float* x_proj_w  = (const float*)d_in[10];
  const float* dt_proj_w = (const float*)d_in[11];
  const float* dt_proj_b = (const float*)d_in[12];
  const float* A_log     = (const float*)d_in[13];
  const float* Dvec      = (const float*)d_in[14];
  const float* out_proj_w= (const float*)d_in[15];
  float* out = (float*)d_out;

  auto al = [](size_t vv) { return (vv + 255) & ~(size_t)255; };

  size_t w_in_sz  = al((size_t)NPAD_IN * KP_IN * 2);
  size_t w_out_sz = al((size_t)NPAD_OUT * KP_OUT * 2);
  size_t w_x_sz   = al((size_t)NPAD_X * KP_OUT * 2);
  size_t w_d_sz   = al((size_t)NPAD_DT * KP_DT * 2);
  size_t fixed = 2 * (w_in_sz + w_out_sz + w_x_sz + w_d_sz);

  auto calc = [&](int bc) -> size_t {
    size_t Mc = (size_t)bc * L_;
    size_t s = fixed;
    s += 2 * al(Mc * KP_IN * 2);              // seq hi/lo
    s += al((size_t)bc * COMB_ * NPOS * 4);   // P
    s += al((size_t)bc * NPOS * DIMC * 4);    // Y
    s += al((size_t)bc * DIMC * 4);           // y0
    s += al(Mc * DXZ * 4);                    // xz
    s += 2 * al(Mc * KP_OUT * 2);             // u hi/lo
    s += al(Mc * DBLP * 4);                   // dbl (padded)
    s += 2 * al(Mc * KP_DT * 2);              // dt hi/lo
    s += al(Mc * DINNER * 4);                 // dt fp32
    s += 2 * al(Mc * KP_OUT * 2);             // y hi/lo
    return s;
  };
  int Bc = 64;
  while (Bc > 1 && calc(Bc) > ws_size) Bc >>= 1;

  size_t Mc = (size_t)Bc * L_;
  char* base = (char*)d_ws;
  size_t off = 0;
  unsigned short* Wih = (unsigned short*)(base + off); off += w_in_sz;
  unsigned short* Wil = (unsigned short*)(base + off); off += w_in_sz;
  unsigned short* Woh = (unsigned short*)(base + off); off += w_out_sz;
  unsigned short* Wol = (unsigned short*)(base + off); off += w_out_sz;
  unsigned short* Wxh = (unsigned short*)(base + off); off += w_x_sz;
  unsigned short* Wxl = (unsigned short*)(base + off); off += w_x_sz;
  unsigned short* Wdh = (unsigned short*)(base + off); off += w_d_sz;
  unsigned short* Wdl = (unsigned short*)(base + off); off += w_d_sz;
  unsigned short* seqh = (unsigned short*)(base + off); off += al(Mc * KP_IN * 2);
  unsigned short* seql = (unsigned short*)(base + off); off += al(Mc * KP_IN * 2);
  float* Pb   = (float*)(base + off); off += al((size_t)Bc * COMB_ * NPOS * 4);
  float* Yb   = (float*)(base + off); off += al((size_t)Bc * NPOS * DIMC * 4);
  float* y0b  = (float*)(base + off); off += al((size_t)Bc * DIMC * 4);
  float* xzb  = (float*)(base + off); off += al(Mc * DXZ * 4);
  unsigned short* vhb = (unsigned short*)(base + off); off += al(Mc * KP_OUT * 2);
  unsigned short* vlb = (unsigned short*)(base + off); off += al(Mc * KP_OUT * 2);
  float* dblb = (float*)(base + off); off += al(Mc * DBLP * 4);
  unsigned short* dth = (unsigned short*)(base + off); off += al(Mc * KP_DT * 2);
  unsigned short* dtl = (unsigned short*)(base + off); off += al(Mc * KP_DT * 2);
  float* dtb  = (float*)(base + off); off += al(Mc * DINNER * 4);
  unsigned short* yhb = (unsigned short*)(base + off); off += al(Mc * KP_OUT * 2);
  unsigned short* ylb = (unsigned short*)(base + off); off += al(Mc * KP_OUT * 2);

  // split weights (once per call)
  wsplit_kernel<<<dim3((KP_IN + 255) / 256, NPAD_IN), 256, 0, stream>>>(
      in_proj_w, DXZ, DMODEL, Wih, Wil, KP_IN);
  wsplit_kernel<<<dim3((KP_OUT + 255) / 256, NPAD_OUT), 256, 0, stream>>>(
      out_proj_w, DMODEL, DINNER, Woh, Wol, KP_OUT);
  wsplit_kernel<<<dim3((KP_OUT + 255) / 256, NPAD_X), 256, 0, stream>>>(
      x_proj_w, DBLP - 15, DINNER, Wxh, Wxl, KP_OUT);   // N=113
  wsplit_kernel<<<dim3((KP_DT + 255) / 256, NPAD_DT), 256, 0, stream>>>(
      dt_proj_w, DINNER, DTRANK, Wdh, Wdl, KP_DT);

  for (int b0 = 0; b0 < BATCH; b0 += Bc) {
    int Mci = Bc * L_;
    // PPM
    pool_kernel<<<dim3((COMB_ * NPOS + 255) / 256, Bc), 256, 0, stream>>>(x, pc, Pb, b0);
    cbr_small_kernel<<<dim3(DIMC, Bc), 256, 0, stream>>>(Pb, conv_w, bn_gamma, bn_beta,
                                                         bn_mean, bn_var, Yb);
    cbr0_kernel<<<dim3(DIMC, Bc), 256, 0, stream>>>(x, pc, conv_w, bn_gamma, bn_beta,
                                                    bn_mean, bn_var, y0b, b0);
    seq_kernel<<<dim3(L_, Bc), 256, 0, stream>>>(x, pc, y0b, Yb, seqh, seql, b0);
    // in_proj: xz = seq @ in_proj_w^T  (split-bf16 MFMA)
    mfma_gemm_kernel<<<dim3(NPAD_IN / 128, Mci / 128), 256, 0, stream>>>(
        seqh, seql, KP_IN, Wih, Wil, xzb, DXZ, Mci, DXZ, 0, nullptr, nullptr, 0);
    // conv1d + silu -> split-bf16 u
    conv1d_kernel<<<dim3((KP_OUT + 255) / 256, Mci), 256, 0, stream>>>(
        xzb, conv1d_w, conv1d_b, vhb, vlb);
    // x_proj (MFMA): dbl = u @ x_proj_w^T, padded stride
    mfma_gemm_kernel<<<dim3(NPAD_X / 128, Mci / 128), 256, 0, stream>>>(
        vhb, vlb, KP_OUT, Wxh, Wxl, dblb, DBLP, Mci, DBLP - 15, 0, nullptr, nullptr, 0);
    // split dt columns
    split_dt_kernel<<<(Mci * KP_DT + 255) / 256, 256, 0, stream>>>(dblb, dth, dtl, Mci);
    // dt_proj (MFMA) + bias + softplus
    mfma_gemm_kernel<<<dim3(NPAD_DT / 128, Mci / 128), 256, 0, stream>>>(
        dth, dtl, KP_DT, Wdh, Wdl, dtb, DINNER, Mci, DINNER, 1, dt_proj_b, nullptr, 0);
    // scan -> split-bf16 y
    scan_kernel<<<dim3((KP_OUT + 255) / 256, Bc), 256, 0, stream>>>(
        dtb, vhb, vlb, xzb, dblb, A_log, Dvec, yhb, ylb);
    // out_proj (split-bf16 MFMA), transposed write into d_out
    mfma_gemm_kernel<<<dim3(NPAD_OUT / 128, Mci / 128), 256, 0, stream>>>(
        yhb, ylb, KP_OUT, Woh, Wol, nullptr, 0, Mci, DMODEL, 2, nullptr, out, b0);
  }
}

// Round 4
// 4149.002 us; speedup vs baseline: 2.4097x; 1.1252x over previous
//
#include <hip/hip_runtime.h>
#include <hip/hip_bf16.h>
#include <math.h>

#define H_ 16
#define W_ 16
#define L_ 256
#define BATCH 64
#define CIMG 512
#define CPC 256
#define COMB_ 770
#define DIMC 128
#define DMODEL 1282
#define DINNER 2564
#define DXZ 5128
#define DTRANK 81
#define NSTATE 16
#define NPOS 275   // 25 + 81 + 169
#define DBLP 128   // padded stride of dbl rows (81 dt | 16 B | 16 C | pad)

#define KP_IN 1312     // 1282 padded to mult of 32
#define KP_OUT 2592    // 2564 padded to mult of 32
#define KP_DT 96       // 81 padded to mult of 32
#define NPAD_IN 5248   // 5128 padded to mult of 128
#define NPAD_OUT 1408  // 1282 padded to mult of 128
#define NPAD_X 128     // 113 padded
#define NPAD_DT 2688   // 2564 padded

typedef __attribute__((ext_vector_type(8))) short short8;
typedef __attribute__((ext_vector_type(4))) float f32x4;

// ---------------------------------------------------------------------------
// helpers
// ---------------------------------------------------------------------------
__device__ __forceinline__ float comb_val(const float* __restrict__ x,
                                          const float* __restrict__ pc,
                                          int bg, int c, int h, int w) {
  if (c < CIMG)    return x[(((size_t)bg * CIMG + c) << 8) + (h << 4) + w];
  if (c == CIMG)   return -0.3f + 0.04f * (float)w;
  if (c == CIMG+1) return -0.3f + 0.04f * (float)h;
  return pc[bg * CPC + (c - (CIMG + 2))];
}

__device__ __forceinline__ void split_bf16(float v, unsigned short& h, unsigned short& l) {
  __hip_bfloat16 hb = __float2bfloat16(v);
  h = __builtin_bit_cast(unsigned short, hb);
  float r = v - __bfloat162float(hb);
  __hip_bfloat16 lb = __float2bfloat16(r);
  l = __builtin_bit_cast(unsigned short, lb);
}

__device__ __forceinline__ float bf16_val(unsigned short u) {
  return __bfloat162float(__builtin_bit_cast(__hip_bfloat16, u));
}

__device__ __forceinline__ void idx_to_scale(int idx, int& s, int& o, int& p, int& base) {
  if (idx < 25)       { s = 5;  base = 0; }
  else if (idx < 106) { s = 9;  base = 25; }
  else                { s = 13; base = 106; }
  int r = idx - base;
  o = r / s; p = r - o * s;
}

// ---------------------------------------------------------------------------
// W-split: fp32 [N,K] -> bf16 hi/lo [Npad,Kp], zero-padded
// ---------------------------------------------------------------------------
__global__ __launch_bounds__(256) void wsplit_kernel(
    const float* __restrict__ W, int N, int K,
    unsigned short* __restrict__ Wh, unsigned short* __restrict__ Wl, int Kp) {
  int k = blockIdx.x * 256 + threadIdx.x;
  if (k >= Kp) return;
  int n = blockIdx.y;
  float v = (n < N && k < K) ? W[(size_t)n * K + k] : 0.f;
  unsigned short h, l;
  split_bf16(v, h, l);
  Wh[(size_t)n * Kp + k] = h;
  Wl[(size_t)n * Kp + k] = l;
}

// ---------------------------------------------------------------------------
// K1: adaptive-avg-pool of comb for scales {5,9,13} -> P[bl][c][idx(275)]
// ---------------------------------------------------------------------------
__global__ __launch_bounds__(256) void pool_kernel(
    const float* __restrict__ x, const float* __restrict__ pc,
    float* __restrict__ P, int b0) {
  int t = blockIdx.x * 256 + threadIdx.x;
  if (t >= COMB_ * NPOS) return;
  int bl = blockIdx.y;
  int bg = b0 + bl;
  int c = t / NPOS;
  int idx = t - c * NPOS;
  int s, o, p, base; idx_to_scale(idx, s, o, p, base);
  int hs = (o * 16) / s, he = ((o + 1) * 16 + s - 1) / s;
  int ws2 = (p * 16) / s, we = ((p + 1) * 16 + s - 1) / s;
  float sum = 0.f;
  for (int h = hs; h < he; h++)
    for (int w = ws2; w < we; w++)
      sum += comb_val(x, pc, bg, c, h, w);
  P[((size_t)bl * COMB_ + c) * NPOS + idx] = sum / (float)((he - hs) * (we - ws2));
}

// ---------------------------------------------------------------------------
// K2: 1x1 conv + BN + ReLU6 on pooled maps (scales 1..3) -> Y[bl][idx][d]
// ---------------------------------------------------------------------------
__global__ __launch_bounds__(256) void cbr_small_kernel(
    const float* __restrict__ P, const float* __restrict__ conv_w,
    const float* __restrict__ gamma, const float* __restrict__ beta,
    const float* __restrict__ mean, const float* __restrict__ var,
    float* __restrict__ Y) {
  int d = blockIdx.x, bl = blockIdx.y;
  __shared__ float wsm[3 * COMB_];
  for (int e = threadIdx.x; e < 3 * COMB_; e += 256) {
    int i = e / COMB_, c = e - i * COMB_;
    wsm[e] = conv_w[((size_t)(i + 1) * DIMC + d) * COMB_ + c];
  }
  __syncthreads();
  for (int idx = threadIdx.x; idx < NPOS; idx += 256) {
    int i = (idx < 25) ? 1 : (idx < 106 ? 2 : 3);
    const float* wr = &wsm[(i - 1) * COMB_];
    const float* pr = &P[(size_t)bl * COMB_ * NPOS + idx];
    float acc = 0.f;
    for (int c = 0; c < COMB_; c++) acc += wr[c] * pr[(size_t)c * NPOS];
    int bi = i * DIMC + d;
    float inv = rsqrtf(var[bi] + 1e-5f) * gamma[bi];
    float bs = beta[bi] - mean[bi] * inv;
    float v = acc * inv + bs;
    v = fminf(fmaxf(v, 0.f), 6.f);
    Y[((size_t)bl * NPOS + idx) * DIMC + d] = v;
  }
}

// ---------------------------------------------------------------------------
// K3: scale-0 path: CBR at full res then spatial mean -> y0[bl][d]
// ---------------------------------------------------------------------------
__global__ __launch_bounds__(256) void cbr0_kernel(
    const float* __restrict__ x, const float* __restrict__ pc,
    const float* __restrict__ conv_w,
    const float* __restrict__ gamma, const float* __restrict__ beta,
    const float* __restrict__ mean, const float* __restrict__ var,
    float* __restrict__ y0, int b0) {
  int d = blockIdx.x, bl = blockIdx.y, bg = b0 + bl;
  __shared__ float w0[COMB_];
  __shared__ float red[4];
  for (int e = threadIdx.x; e < COMB_; e += 256)
    w0[e] = conv_w[(size_t)d * COMB_ + e];
  __syncthreads();
  int l = threadIdx.x;
  int h = l >> 4, w = l & 15;
  float acc = 0.f;
  for (int c = 0; c < CIMG; c++)
    acc += w0[c] * x[(((size_t)bg * CIMG + c) << 8) + l];
  acc += w0[CIMG]     * (-0.3f + 0.04f * (float)w);
  acc += w0[CIMG + 1] * (-0.3f + 0.04f * (float)h);
  for (int c = 0; c < CPC; c++)
    acc += w0[CIMG + 2 + c] * pc[bg * CPC + c];
  float inv = rsqrtf(var[d] + 1e-5f) * gamma[d];
  float bs = beta[d] - mean[d] * inv;
  float v = fminf(fmaxf(acc * inv + bs, 0.f), 6.f);
  #pragma unroll
  for (int off = 32; off > 0; off >>= 1) v += __shfl_down(v, off);
  if ((threadIdx.x & 63) == 0) red[threadIdx.x >> 6] = v;
  __syncthreads();
  if (threadIdx.x == 0)
    y0[bl * DIMC + d] = (red[0] + red[1] + red[2] + red[3]) * (1.f / 256.f);
}

// ---------------------------------------------------------------------------
// K4: assemble seq as split bf16 [bl*L][KP_IN] hi/lo, zero-padded cols
// ---------------------------------------------------------------------------
__global__ __launch_bounds__(256) void seq_kernel(
    const float* __restrict__ x, const float* __restrict__ pc,
    const float* __restrict__ y0, const float* __restrict__ Y,
    unsigned short* __restrict__ seqh, unsigned short* __restrict__ seql, int b0) {
  int l = blockIdx.x, bl = blockIdx.y, bg = b0 + bl;
  int h = l >> 4, w = l & 15;
  size_t rb = ((size_t)bl * L_ + l) * KP_IN;
  for (int c = threadIdx.x; c < KP_IN; c += 256) {
    float v;
    if (c < COMB_) {
      v = comb_val(x, pc, bg, c, h, w);
    } else if (c < COMB_ + DIMC) {
      v = y0[bl * DIMC + (c - COMB_)];
    } else if (c < DMODEL) {
      int cc = c - (COMB_ + DIMC);
      int si = cc >> 7;
      int d = cc & 127;
      int s    = (si == 0) ? 5 : ((si == 1) ? 9 : 13);
      int base = (si == 0) ? 0 : ((si == 1) ? 25 : 106);
      float srch = (h + 0.5f) * (float)s * (1.f / 16.f) - 0.5f;
      srch = fminf(fmaxf(srch, 0.f), (float)(s - 1));
      int o0 = (int)floorf(srch);
      float fh = srch - (float)o0;
      int o1 = min(o0 + 1, s - 1);
      float srcw = (w + 0.5f) * (float)s * (1.f / 16.f) - 0.5f;
      srcw = fminf(fmaxf(srcw, 0.f), (float)(s - 1));
      int p0 = (int)floorf(srcw);
      float fw = srcw - (float)p0;
      int p1 = min(p0 + 1, s - 1);
      const float* Yb = &Y[((size_t)bl * NPOS + base) * DIMC + d];
      float v00 = Yb[(size_t)(o0 * s + p0) * DIMC];
      float v01 = Yb[(size_t)(o0 * s + p1) * DIMC];
      float v10 = Yb[(size_t)(o1 * s + p0) * DIMC];
      float v11 = Yb[(size_t)(o1 * s + p1) * DIMC];
      v = (1.f - fh) * ((1.f - fw) * v00 + fw * v01)
        +        fh  * ((1.f - fw) * v10 + fw * v11);
    } else {
      v = 0.f;
    }
    unsigned short hh, ll;
    split_bf16(v, hh, ll);
    seqh[rb + c] = hh;
    seql[rb + c] = ll;
  }
}

// ---------------------------------------------------------------------------
// K5: fused split-bf16 MFMA GEMM (single K-pass).
// C = (Ah+Al)[M,Kp] * (Bh+Bl)[Npad,Kp]^T via Ah*Bh + Ah*Bl + Al*Bh.
// 128x128 tile, BK=32, 4 waves, 16x16x32; 48 MFMA per barrier window.
// XOR-swizzled LDS (source-side permute keeps global_load_lds contiguous).
// XCD-aware block remap (round-robin lin%8 -> contiguous per-XCD n-range).
// mode 0: plain store. mode 1: +bias[n], softplus. mode 2: out[b][gn][l].
// ---------------------------------------------------------------------------
__global__ __launch_bounds__(256) void mfma_gemm_kernel(
    const unsigned short* __restrict__ Ah, const unsigned short* __restrict__ Al, int Kp,
    const unsigned short* __restrict__ Bh, const unsigned short* __restrict__ Bl,
    float* __restrict__ C, int ldc, int M, int N, int mode,
    const float* __restrict__ bias,
    float* __restrict__ outT, int b0) {
  __shared__ __align__(16) unsigned short Ash[128 * 32];
  __shared__ __align__(16) unsigned short Asl[128 * 32];
  __shared__ __align__(16) unsigned short Bsh[128 * 32];
  __shared__ __align__(16) unsigned short Bsl[128 * 32];
  int tid = threadIdx.x;
  int lane = tid & 63;
  int wave = tid >> 6;

  // XCD-aware remap: round-robin lin%8 gets a contiguous vid range (m-fast)
  int gx = gridDim.x, gy = gridDim.y;
  int lin = blockIdx.y * gx + blockIdx.x;
  int total = gx * gy;
  int mt, nt;
  if ((total & 7) == 0) {
    int vid = (lin & 7) * (total >> 3) + (lin >> 3);
    mt = vid % gy; nt = vid / gy;
  } else {
    mt = blockIdx.y; nt = blockIdx.x;
  }
  int m0 = mt << 7, n0 = nt << 7;
  int wm = (wave & 1) << 6, wn = (wave >> 1) << 6;
  f32x4 acc[4][4] = {};
  int mrow = lane & 15;
  // XOR-swizzled k-chunk offset (elements) for this lane's fragment reads
  int kx = (((lane >> 4) ^ ((lane >> 2) & 3)) << 3);

  for (int k0 = 0; k0 < Kp; k0 += 32) {
    #pragma unroll
    for (int j = 0; j < 2; j++) {
      int c = (j << 8) + tid;          // chunk id 0..511
      int r = c >> 2;                  // row in tile
      int kc = (((c & 3) ^ ((r >> 2) & 3)) << 3);  // swizzled source k-offset
      size_t ga = (size_t)(m0 + r) * Kp + k0 + kc;
      size_t gb = (size_t)(n0 + r) * Kp + k0 + kc;
      __builtin_amdgcn_global_load_lds(
          (const __attribute__((address_space(1))) unsigned int*)(Ah + ga),
          (__attribute__((address_space(3))) unsigned int*)(&Ash[c << 3]), 16, 0, 0);
      __builtin_amdgcn_global_load_lds(
          (const __attribute__((address_space(1))) unsigned int*)(Al + ga),
          (__attribute__((address_space(3))) unsigned int*)(&Asl[c << 3]), 16, 0, 0);
      __builtin_amdgcn_global_load_lds(
          (const __attribute__((address_space(1))) unsigned int*)(Bh + gb),
          (__attribute__((address_space(3))) unsigned int*)(&Bsh[c << 3]), 16, 0, 0);
      __builtin_amdgcn_global_load_lds(
          (const __attribute__((address_space(1))) unsigned int*)(Bl + gb),
          (__attribute__((address_space(3))) unsigned int*)(&Bsl[c << 3]), 16, 0, 0);
    }
    __syncthreads();
    short8 ah[4], al[4], bh[4], blo[4];
    #pragma unroll
    for (int i = 0; i < 4; i++) {
      int ro = (wm + (i << 4) + mrow) * 32 + kx;
      ah[i] = *(const short8*)&Ash[ro];
      al[i] = *(const short8*)&Asl[ro];
    }
    #pragma unroll
    for (int j = 0; j < 4; j++) {
      int ro = (wn + (j << 4) + mrow) * 32 + kx;
      bh[j]  = *(const short8*)&Bsh[ro];
      blo[j] = *(const short8*)&Bsl[ro];
    }
    #pragma unroll
    for (int i = 0; i < 4; i++)
      #pragma unroll
      for (int j = 0; j < 4; j++) {
        acc[i][j] = __builtin_amdgcn_mfma_f32_16x16x32_bf16(ah[i], bh[j],  acc[i][j], 0, 0, 0);
        acc[i][j] = __builtin_amdgcn_mfma_f32_16x16x32_bf16(ah[i], blo[j], acc[i][j], 0, 0, 0);
        acc[i][j] = __builtin_amdgcn_mfma_f32_16x16x32_bf16(al[i], bh[j],  acc[i][j], 0, 0, 0);
      }
    __syncthreads();
  }

  int n_l = lane & 15, m_l = (lane >> 4) << 2;
  #pragma unroll
  for (int i = 0; i < 4; i++) {
    int gm0 = m0 + wm + (i << 4) + m_l;
    #pragma unroll
    for (int j = 0; j < 4; j++) {
      int gn = n0 + wn + (j << 4) + n_l;
      if (gn >= N) continue;
      if (mode == 2) {
        int bb = b0 + (gm0 >> 8), l0 = gm0 & 255;
        *(f32x4*)&outT[(((size_t)bb * DMODEL + gn) << 8) + l0] = acc[i][j];
      } else if (mode == 1) {
        float bv = bias[gn];
        #pragma unroll
        for (int r = 0; r < 4; r++) {
          float vv = acc[i][j][r] + bv;
          vv = (vv > 20.f) ? vv : log1pf(expf(vv));
          C[(size_t)(gm0 + r) * ldc + gn] = vv;
        }
      } else {
        #pragma unroll
        for (int r = 0; r < 4; r++)
          C[(size_t)(gm0 + r) * ldc + gn] = acc[i][j][r];
      }
    }
  }
}

// ---------------------------------------------------------------------------
// K6: depthwise causal conv1d (k=4) + bias + silu -> split bf16 u [m][KP_OUT]
// ---------------------------------------------------------------------------
__global__ __launch_bounds__(256) void conv1d_kernel(
    const float* __restrict__ xz, const float* __restrict__ cw,
    const float* __restrict__ cb,
    unsigned short* __restrict__ vh, unsigned short* __restrict__ vl) {
  int d = blockIdx.x * 256 + threadIdx.x;
  if (d >= KP_OUT) return;
  int m = blockIdx.y;
  size_t o = (size_t)m * KP_OUT + d;
  if (d >= DINNER) { vh[o] = 0; vl[o] = 0; return; }
  int l = m & 255;
  float acc = cb[d];
  #pragma unroll
  for (int j = 0; j < 4; j++) {
    int ll = l - 3 + j;
    if (ll >= 0) acc += cw[d * 4 + j] * xz[(size_t)(m - 3 + j) * DXZ + d];
  }
  float s = acc / (1.f + __expf(-acc));
  unsigned short hh, llv;
  split_bf16(s, hh, llv);
  vh[o] = hh; vl[o] = llv;
}

// ---------------------------------------------------------------------------
// K6b: split dt columns of dbl (fp32, stride DBLP) -> dth/dtl [m][KP_DT]
// ---------------------------------------------------------------------------
__global__ __launch_bounds__(256) void split_dt_kernel(
    const float* __restrict__ dbl,
    unsigned short* __restrict__ dth, unsigned short* __restrict__ dtl, int M) {
  int t = blockIdx.x * 256 + threadIdx.x;
  if (t >= M * KP_DT) return;
  int m = t / KP_DT, k = t - m * KP_DT;
  float v = (k < DTRANK) ? dbl[(size_t)m * DBLP + k] : 0.f;
  unsigned short h, l;
  split_bf16(v, h, l);
  dth[t] = h; dtl[t] = l;
}

// ---------------------------------------------------------------------------
// K7: selective scan. u from split bf16; writes gated y as split bf16
// ---------------------------------------------------------------------------
__global__ __launch_bounds__(256) void scan_kernel(
    const float* __restrict__ dtv,
    const unsigned short* __restrict__ vh, const unsigned short* __restrict__ vl,
    const float* __restrict__ xz,
    const float* __restrict__ dbl, const float* __restrict__ A_log,
    const float* __restrict__ Dv,
    unsigned short* __restrict__ yh, unsigned short* __restrict__ yl) {
  int d = blockIdx.x * 256 + threadIdx.x;
  if (d >= KP_OUT) return;
  int bl = blockIdx.y;
  if (d >= DINNER) {   // zero-fill K padding
    for (int l = 0; l < L_; l++) {
      size_t m = (size_t)bl * L_ + l;
      yh[m * KP_OUT + d] = 0;
      yl[m * KP_OUT + d] = 0;
    }
    return;
  }
  float A[NSTATE], hst[NSTATE];
  #pragma unroll
  for (int n = 0; n < NSTATE; n++) {
    A[n] = -__expf(A_log[d * NSTATE + n]);
    hst[n] = 0.f;
  }
  float Dd = Dv[d];
  for (int l = 0; l < L_; l++) {
    size_t m = (size_t)bl * L_ + l;
    float dt = dtv[m * DINNER + d];
    float uu = bf16_val(vh[m * KP_OUT + d]) + bf16_val(vl[m * KP_OUT + d]);
    float zz = xz[m * DXZ + DINNER + d];
    const float* bc = &dbl[m * DBLP];
    float du = dt * uu;
    float y = 0.f;
    #pragma unroll
    for (int n = 0; n < NSTATE; n++) {
      float dA = __expf(dt * A[n]);
      hst[n] = dA * hst[n] + du * bc[DTRANK + n];
      y += hst[n] * bc[DTRANK + NSTATE + n];
    }
    float val = (y + uu * Dd) * (zz / (1.f + __expf(-zz)));
    unsigned short hh, ll;
    split_bf16(val, hh, ll);
    yh[m * KP_OUT + d] = hh;
    yl[m * KP_OUT + d] = ll;
  }
}

// ---------------------------------------------------------------------------
// launch
// ---------------------------------------------------------------------------
extern "C" void kernel_launch(void* const* d_in, const int* in_sizes, int n_in,
                              void* d_out, int out_size, void* d_ws, size_t ws_size,
                              hipStream_t stream) {
  const float* x         = (const float*)d_in[0];
  const float* pc        = (const float*)d_in[1];
  const float* conv_w    = (const float*)d_in[2];
  const float* bn_gamma  = (const float*)d_in[3];
  const float* bn_beta   = (const float*)d_in[4];
  const float* bn_mean   = (const float*)d_in[5];
  const float* bn_var    = (const float*)d_in[6];
  const float* in_proj_w = (const float*)d_in[7];
  const float* conv1d_w  = (const float*)d_in[8];
  const float* conv1d_b  = (const float*)d_in[9];
  const float* x_proj_w  = (const float*)d_in[10];
  const float* dt_proj_w = (const float*)d_in[11];
  const float* dt_proj_b = (const float*)d_in[12];
  const float* A_log     = (const float*)d_in[13];
  const float* Dvec      = (const float*)d_in[14];
  const float* out_proj_w= (const float*)d_in[15];
  float* out = (float*)d_out;

  auto al = [](size_t vv) { return (vv + 255) & ~(size_t)255; };

  size_t w_in_sz  = al((size_t)NPAD_IN * KP_IN * 2);
  size_t w_out_sz = al((size_t)NPAD_OUT * KP_OUT * 2);
  size_t w_x_sz   = al((size_t)NPAD_X * KP_OUT * 2);
  size_t w_d_sz   = al((size_t)NPAD_DT * KP_DT * 2);
  size_t fixed = 2 * (w_in_sz + w_out_sz + w_x_sz + w_d_sz);

  auto calc = [&](int bc) -> size_t {
    size_t Mc = (size_t)bc * L_;
    size_t s = fixed;
    s += 2 * al(Mc * KP_IN * 2);              // seq hi/lo
    s += al((size_t)bc * COMB_ * NPOS * 4);   // P
    s += al((size_t)bc * NPOS * DIMC * 4);    // Y
    s += al((size_t)bc * DIMC * 4);           // y0
    s += al(Mc * DXZ * 4);                    // xz
    s += 2 * al(Mc * KP_OUT * 2);             // u hi/lo
    s += al(Mc * DBLP * 4);                   // dbl (padded)
    s += 2 * al(Mc * KP_DT * 2);              // dt hi/lo
    s += al(Mc * DINNER * 4);                 // dt fp32
    s += 2 * al(Mc * KP_OUT * 2);             // y hi/lo
    return s;
  };
  int Bc = 64;
  while (Bc > 1 && calc(Bc) > ws_size) Bc >>= 1;

  size_t Mc = (size_t)Bc * L_;
  char* base = (char*)d_ws;
  size_t off = 0;
  unsigned short* Wih = (unsigned short*)(base + off); off += w_in_sz;
  unsigned short* Wil = (unsigned short*)(base + off); off += w_in_sz;
  unsigned short* Woh = (unsigned short*)(base + off); off += w_out_sz;
  unsigned short* Wol = (unsigned short*)(base + off); off += w_out_sz;
  unsigned short* Wxh = (unsigned short*)(base + off); off += w_x_sz;
  unsigned short* Wxl = (unsigned short*)(base + off); off += w_x_sz;
  unsigned short* Wdh = (unsigned short*)(base + off); off += w_d_sz;
  unsigned short* Wdl = (unsigned short*)(base + off); off += w_d_sz;
  unsigned short* seqh = (unsigned short*)(base + off); off += al(Mc * KP_IN * 2);
  unsigned short* seql = (unsigned short*)(base + off); off += al(Mc * KP_IN * 2);
  float* Pb   = (float*)(base + off); off += al((size_t)Bc * COMB_ * NPOS * 4);
  float* Yb   = (float*)(base + off); off += al((size_t)Bc * NPOS * DIMC * 4);
  float* y0b  = (float*)(base + off); off += al((size_t)Bc * DIMC * 4);
  float* xzb  = (float*)(base + off); off += al(Mc * DXZ * 4);
  unsigned short* vhb = (unsigned short*)(base + off); off += al(Mc * KP_OUT * 2);
  unsigned short* vlb = (unsigned short*)(base + off); off += al(Mc * KP_OUT * 2);
  float* dblb = (float*)(base + off); off += al(Mc * DBLP * 4);
  unsigned short* dth = (unsigned short*)(base + off); off += al(Mc * KP_DT * 2);
  unsigned short* dtl = (unsigned short*)(base + off); off += al(Mc * KP_DT * 2);
  float* dtb  = (float*)(base + off); off += al(Mc * DINNER * 4);
  unsigned short* yhb = (unsigned short*)(base + off); off += al(Mc * KP_OUT * 2);
  unsigned short* ylb = (unsigned short*)(base + off); off += al(Mc * KP_OUT * 2);

  // split weights (once per call)
  wsplit_kernel<<<dim3((KP_IN + 255) / 256, NPAD_IN), 256, 0, stream>>>(
      in_proj_w, DXZ, DMODEL, Wih, Wil, KP_IN);
  wsplit_kernel<<<dim3((KP_OUT + 255) / 256, NPAD_OUT), 256, 0, stream>>>(
      out_proj_w, DMODEL, DINNER, Woh, Wol, KP_OUT);
  wsplit_kernel<<<dim3((KP_OUT + 255) / 256, NPAD_X), 256, 0, stream>>>(
      x_proj_w, DBLP - 15, DINNER, Wxh, Wxl, KP_OUT);   // N=113
  wsplit_kernel<<<dim3((KP_DT + 255) / 256, NPAD_DT), 256, 0, stream>>>(
      dt_proj_w, DINNER, DTRANK, Wdh, Wdl, KP_DT);

  for (int b0 = 0; b0 < BATCH; b0 += Bc) {
    int Mci = Bc * L_;
    // PPM
    pool_kernel<<<dim3((COMB_ * NPOS + 255) / 256, Bc), 256, 0, stream>>>(x, pc, Pb, b0);
    cbr_small_kernel<<<dim3(DIMC, Bc), 256, 0, stream>>>(Pb, conv_w, bn_gamma, bn_beta,
                                                         bn_mean, bn_var, Yb);
    cbr0_kernel<<<dim3(DIMC, Bc), 256, 0, stream>>>(x, pc, conv_w, bn_gamma, bn_beta,
                                                    bn_mean, bn_var, y0b, b0);
    seq_kernel<<<dim3(L_, Bc), 256, 0, stream>>>(x, pc, y0b, Yb, seqh, seql, b0);
    // in_proj (fused split-bf16 MFMA)
    mfma_gemm_kernel<<<dim3(NPAD_IN / 128, Mci / 128), 256, 0, stream>>>(
        seqh, seql, KP_IN, Wih, Wil, xzb, DXZ, Mci, DXZ, 0, nullptr, nullptr, 0);
    // conv1d + silu -> split-bf16 u
    conv1d_kernel<<<dim3((KP_OUT + 255) / 256, Mci), 256, 0, stream>>>(
        xzb, conv1d_w, conv1d_b, vhb, vlb);
    // x_proj (fused MFMA): dbl = u @ x_proj_w^T, padded stride
    mfma_gemm_kernel<<<dim3(NPAD_X / 128, Mci / 128), 256, 0, stream>>>(
        vhb, vlb, KP_OUT, Wxh, Wxl, dblb, DBLP, Mci, DBLP - 15, 0, nullptr, nullptr, 0);
    // split dt columns
    split_dt_kernel<<<(Mci * KP_DT + 255) / 256, 256, 0, stream>>>(dblb, dth, dtl, Mci);
    // dt_proj (fused MFMA) + bias + softplus
    mfma_gemm_kernel<<<dim3(NPAD_DT / 128, Mci / 128), 256, 0, stream>>>(
        dth, dtl, KP_DT, Wdh, Wdl, dtb, DINNER, Mci, DINNER, 1, dt_proj_b, nullptr, 0);
    // scan -> split-bf16 y
    scan_kernel<<<dim3((KP_OUT + 255) / 256, Bc), 256, 0, stream>>>(
        dtb, vhb, vlb, xzb, dblb, A_log, Dvec, yhb, ylb);
    // out_proj (fused MFMA), transposed write into d_out
    mfma_gemm_kernel<<<dim3(NPAD_OUT / 128, Mci / 128), 256, 0, stream>>>(
        yhb, ylb, KP_OUT, Woh, Wol, nullptr, 0, Mci, DMODEL, 2, nullptr, out, b0);
  }
}